// Round 2
// baseline (5065.380 us; speedup 1.0000x reference)
//
#include <hip/hip_runtime.h>
#include <hip/hip_bf16.h>
#include <hip/hip_cooperative_groups.h>
#include <cstdint>

namespace cg = cooperative_groups;

// Problem constants
constexpr int kB = 512;      // batch
constexpr int kT = 80;       // encoder seq len
constexpr int kC = 512;      // in_channels
constexpr int kH = 256;      // hidden
constexpr int kV = 6625;     // classes
constexpr int kGIN = kC + kV; // 7137, gru_wih leading dim

typedef __attribute__((ext_vector_type(8))) short short8;
typedef __attribute__((ext_vector_type(4))) float floatx4;

__device__ __forceinline__ float fast_tanh(float x) {
  float e = __expf(2.f * x);
  return 1.f - 2.f / (e + 1.f);
}
__device__ __forceinline__ float fast_sig(float x) {
  return 1.f / (1.f + __expf(-x));
}

__device__ __forceinline__ void gld_lds16(const void* g, void* l) {
  __builtin_amdgcn_global_load_lds(
      (const __attribute__((address_space(1))) void*)(uintptr_t)g,
      (__attribute__((address_space(3))) void*)(uintptr_t)l, 16, 0, 0);
}

// ---------------------------------------------------------------------------
// fp32 -> bf16 conversion (gen_w)
// ---------------------------------------------------------------------------
__global__ __launch_bounds__(256) void cvt_bf16(const float* __restrict__ x,
                                                __hip_bfloat16* __restrict__ y,
                                                int n) {
  int i = blockIdx.x * 256 + threadIdx.x;
  if (i < n) y[i] = __float2bfloat16(x[i]);
}

// ---------------------------------------------------------------------------
// One-time transpose: WT[v][n] = wih[n][kC + v]  (v<6625, n<768)
// Makes the per-step one-hot gather a contiguous 3KB row read.
// ---------------------------------------------------------------------------
__global__ __launch_bounds__(256) void wt_transpose(const float* __restrict__ wih,
                                                    float* __restrict__ WT) {
  __shared__ float tile[32][33];
  const int vb = blockIdx.x * 32, nb = blockIdx.y * 32;
  const int tx = threadIdx.x & 31, ty0 = threadIdx.x >> 5;  // 32 x 8
#pragma unroll
  for (int i = 0; i < 4; ++i) {
    int n = nb + ty0 + i * 8;
    int v = vb + tx;
    tile[ty0 + i * 8][tx] = (v < kV) ? wih[(size_t)n * kGIN + kC + v] : 0.f;
  }
  __syncthreads();
#pragma unroll
  for (int i = 0; i < 4; ++i) {
    int v = vb + ty0 + i * 8;
    if (v < kV) WT[(size_t)v * 768 + nb + tx] = tile[tx][ty0 + i * 8];
  }
}

// ---------------------------------------------------------------------------
// fp32 tiled GEMM: C[M,N] = A[M,K] * W[N,K]^T  (proj = inputs @ i2h_w^T)
// 64x64 tile, BK=16, 256 threads, 4x4 microtile. M=40960, N=256, K=512.
// ---------------------------------------------------------------------------
__global__ __launch_bounds__(256) void proj_gemm(
    const float* __restrict__ A, const float* __restrict__ W,
    float* __restrict__ C) {
  constexpr int lda = kC, ldw = kC, ldc = kH, K = kC;
  __shared__ __align__(16) float As[16][72];
  __shared__ __align__(16) float Ws[16][72];
  const int tid = threadIdx.x;
  const int m0 = blockIdx.x * 64;
  const int n0 = blockIdx.y * 64;
  const int lrow = tid >> 2, lkq = tid & 3;
  const int ty = tid >> 4, tx = tid & 15;
  float acc[4][4] = {};
  for (int k0 = 0; k0 < K; k0 += 16) {
    const float* ap = A + (size_t)(m0 + lrow) * lda + k0 + lkq * 4;
    float4 av = *(const float4*)ap;
    const float* wp = W + (size_t)(n0 + lrow) * ldw + k0 + lkq * 4;
    float4 wv = *(const float4*)wp;
    As[lkq * 4 + 0][lrow] = av.x;
    As[lkq * 4 + 1][lrow] = av.y;
    As[lkq * 4 + 2][lrow] = av.z;
    As[lkq * 4 + 3][lrow] = av.w;
    Ws[lkq * 4 + 0][lrow] = wv.x;
    Ws[lkq * 4 + 1][lrow] = wv.y;
    Ws[lkq * 4 + 2][lrow] = wv.z;
    Ws[lkq * 4 + 3][lrow] = wv.w;
    __syncthreads();
#pragma unroll
    for (int k = 0; k < 16; ++k) {
      float4 a = *(const float4*)&As[k][ty * 4];
      float4 w = *(const float4*)&Ws[k][tx * 4];
      acc[0][0] += a.x * w.x; acc[0][1] += a.x * w.y; acc[0][2] += a.x * w.z; acc[0][3] += a.x * w.w;
      acc[1][0] += a.y * w.x; acc[1][1] += a.y * w.y; acc[1][2] += a.y * w.z; acc[1][3] += a.y * w.w;
      acc[2][0] += a.z * w.x; acc[2][1] += a.z * w.y; acc[2][2] += a.z * w.z; acc[2][3] += a.z * w.w;
      acc[3][0] += a.w * w.x; acc[3][1] += a.w * w.y; acc[3][2] += a.w * w.z; acc[3][3] += a.w * w.w;
    }
    __syncthreads();
  }
#pragma unroll
  for (int i = 0; i < 4; ++i)
#pragma unroll
    for (int j = 0; j < 4; ++j)
      C[(size_t)(m0 + ty * 4 + i) * ldc + n0 + tx * 4 + j] = acc[i][j];
}

// ---------------------------------------------------------------------------
// Cooperative fused recurrence: 256 blocks x 512 threads, 4 grid.sync()/step.
// Phase A: phgh GEMM (64x64 tiles, 2-way K-split -> pgA/pgB partials)
// Phase B: attention per 2 batch rows/block -> ctx
// Phase C: gi GEMM (64x64 tiles, 2-way K-split -> giA/giB) + WT gather
// Phase D: elementwise GRU update, writes hidden + hidd(bf16)
// Weight traffic is GEMM-tiled (64x reuse), not per-block redundant.
// ---------------------------------------------------------------------------
__global__ __launch_bounds__(512) void fused_coop(
    const float* __restrict__ inputs, const float* __restrict__ proj,
    const int* __restrict__ targets,
    const float* __restrict__ h2h_w, const float* __restrict__ h2h_b,
    const float* __restrict__ whh, const float* __restrict__ bhh,
    const float* __restrict__ wih, const float* __restrict__ bih,
    const float* __restrict__ score_w, const float* __restrict__ WT,
    float* __restrict__ pgA, float* __restrict__ pgB,
    float* __restrict__ ctxb, float* __restrict__ giA, float* __restrict__ giB,
    float* __restrict__ hid, __hip_bfloat16* __restrict__ hidd, int S) {
  cg::grid_group grid = cg::this_grid();
  __shared__ __align__(16) float As[32][68];   // k-major A tile, col-swizzled
  __shared__ __align__(16) float Ws[32][72];   // k-major W tile, col-swizzled
  __shared__ __align__(16) float ph_s[2][kH];
  __shared__ __align__(16) float sw_s[kH];
  __shared__ __align__(16) float cst[2][kC];
  __shared__ float e_s[2][kT];
  const int tid = threadIdx.x;
  const int bid = blockIdx.x;
  const int wave = tid >> 6, lane = tid & 63;
  const int sm = tid >> 3, sq = tid & 7;       // staging: row 0..63, k-quad 0..7
  const int ty = tid >> 4, tx = tid & 15;      // compute (tid<256): 16x16

  // init: hidden = 0, score weights to LDS
  hid[bid * 512 + tid] = 0.f;
  if (tid < kH) sw_s[tid] = score_w[tid];
  grid.sync();

  for (int s = 0; s < S; ++s) {
    // ================= phase A: phgh partial GEMM ==================
    {
      const int u = bid;                  // 0..255 = 128 tiles x 2 k-halves
      const int tile = u & 127, kh = u >> 7;
      const int mi = tile & 7, ni = tile >> 3;  // 8 x 16
      const int m0 = mi * 64, n0 = ni * 64;
      const float* Wb = (ni < 4) ? h2h_w : whh;
      const int nb = (ni < 4) ? n0 : n0 - 256;
      const float* bias = (ni < 4) ? h2h_b : bhh;
      const int khb = kh * 128;
      float acc[4][4] = {};
      for (int c = 0; c < 4; ++c) {
        const int k0 = khb + c * 32;
        {  // stage A (hidden rows m0..m0+63, 32 k)
          float4 v = *(const float4*)(hid + (size_t)(m0 + sm) * kH + k0 + sq * 4);
#pragma unroll
          for (int i = 0; i < 4; ++i) {
            int kl = sq * 4 + i;
            As[kl][sm ^ (4 * (kl & 7))] = ((const float*)&v)[i];
          }
        }
        {  // stage W (rows nb..nb+63, 32 k)
          float4 v = *(const float4*)(Wb + (size_t)(nb + sm) * kH + k0 + sq * 4);
#pragma unroll
          for (int i = 0; i < 4; ++i) {
            int kl = sq * 4 + i;
            Ws[kl][sm ^ (8 * sq)] = ((const float*)&v)[i];
          }
        }
        __syncthreads();
        if (tid < 256) {
#pragma unroll
          for (int k = 0; k < 32; ++k) {
            float4 a = *(const float4*)&As[k][(ty * 4) ^ (4 * (k & 7))];
            float4 w = *(const float4*)&Ws[k][(tx * 4) ^ (8 * ((k >> 2) & 7))];
            acc[0][0] += a.x * w.x; acc[0][1] += a.x * w.y; acc[0][2] += a.x * w.z; acc[0][3] += a.x * w.w;
            acc[1][0] += a.y * w.x; acc[1][1] += a.y * w.y; acc[1][2] += a.y * w.z; acc[1][3] += a.y * w.w;
            acc[2][0] += a.z * w.x; acc[2][1] += a.z * w.y; acc[2][2] += a.z * w.z; acc[2][3] += a.z * w.w;
            acc[3][0] += a.w * w.x; acc[3][1] += a.w * w.y; acc[3][2] += a.w * w.z; acc[3][3] += a.w * w.w;
          }
        }
        __syncthreads();
      }
      if (tid < 256) {
        float* dst = kh ? pgB : pgA;
        float4 bb = {0.f, 0.f, 0.f, 0.f};
        if (!kh) bb = *(const float4*)(bias + nb + tx * 4);
#pragma unroll
        for (int i = 0; i < 4; ++i) {
          float4 o;
          o.x = acc[i][0] + bb.x; o.y = acc[i][1] + bb.y;
          o.z = acc[i][2] + bb.z; o.w = acc[i][3] + bb.w;
          *(float4*)(dst + (size_t)(m0 + ty * 4 + i) * 1024 + n0 + tx * 4) = o;
        }
      }
    }
    grid.sync();

    // ================= phase B: attention ==================
    {
      const int r0 = bid * 2;
      {  // ph = pgA + pgB (cols 0..255)
        int r = tid >> 8, h = tid & 255;
        ph_s[r][h] = pgA[(size_t)(r0 + r) * 1024 + h] + pgB[(size_t)(r0 + r) * 1024 + h];
      }
      __syncthreads();
      // e[r][t] = sum_h tanh(proj+ph)*sw   (160 tasks over 8 waves)
      for (int tau = wave; tau < 2 * kT; tau += 8) {
        const int r = tau & 1, t = tau >> 1;
        const float* pp = proj + ((size_t)(r0 + r) * kT + t) * kH + lane * 4;
        float4 pr = *(const float4*)pp;
        float4 ph4 = *(const float4*)&ph_s[r][lane * 4];
        float4 s4 = *(const float4*)&sw_s[lane * 4];
        float part = fast_tanh(pr.x + ph4.x) * s4.x + fast_tanh(pr.y + ph4.y) * s4.y +
                     fast_tanh(pr.z + ph4.z) * s4.z + fast_tanh(pr.w + ph4.w) * s4.w;
#pragma unroll
        for (int off = 32; off > 0; off >>= 1) part += __shfl_xor(part, off);
        if (lane == 0) e_s[r][t] = part;
      }
      __syncthreads();
      // softmax over T=80 (wave r handles row r)
      if (wave < 2) {
        const int r = wave;
        float v0 = e_s[r][lane];
        float v1 = (lane < kT - 64) ? e_s[r][64 + lane] : -1e30f;
        float mx = fmaxf(v0, v1);
#pragma unroll
        for (int off = 32; off > 0; off >>= 1) mx = fmaxf(mx, __shfl_xor(mx, off));
        float x0 = __expf(v0 - mx);
        float x1 = (lane < kT - 64) ? __expf(v1 - mx) : 0.f;
        float smm = x0 + x1;
#pragma unroll
        for (int off = 32; off > 0; off >>= 1) smm += __shfl_xor(smm, off);
        float inv = 1.f / smm;
        e_s[r][lane] = x0 * inv;
        if (lane < kT - 64) e_s[r][64 + lane] = x1 * inv;
      }
      __syncthreads();
      // context: 2 t-streams of f4 columns, combine via LDS
      {
        const int r = tid >> 8, q = tid & 255;
        const int sub = q >> 7, c4 = (q & 127) * 4;
        const float* ib = inputs + (size_t)(r0 + r) * kT * kC + c4;
        float4 a4 = {0.f, 0.f, 0.f, 0.f};
        for (int t = sub; t < kT; t += 2) {
          float a = e_s[r][t];
          float4 v = *(const float4*)(ib + (size_t)t * kC);
          a4.x += a * v.x; a4.y += a * v.y; a4.z += a * v.z; a4.w += a * v.w;
        }
        if (sub) *(float4*)&cst[r][c4] = a4;
        __syncthreads();
        if (!sub) {
          float4 o = *(const float4*)&cst[r][c4];
          o.x += a4.x; o.y += a4.y; o.z += a4.z; o.w += a4.w;
          *(float4*)(ctxb + (size_t)(r0 + r) * kC + c4) = o;
        }
      }
    }
    grid.sync();

    // ================= phase C: gi partial GEMM + gather ==================
    if (bid < 192) {                      // 96 tiles x 2 k-halves
      const int tile = bid >> 1, kh = bid & 1;
      const int mi = tile & 7, ni = tile >> 3;  // 8 x 12
      const int m0 = mi * 64, n0 = ni * 64;
      const int khb = kh * 256;
      float acc[4][4] = {};
      for (int c = 0; c < 8; ++c) {
        const int k0 = khb + c * 32;
        {  // stage A (ctx rows)
          float4 v = *(const float4*)(ctxb + (size_t)(m0 + sm) * kC + k0 + sq * 4);
#pragma unroll
          for (int i = 0; i < 4; ++i) {
            int kl = sq * 4 + i;
            As[kl][sm ^ (4 * (kl & 7))] = ((const float*)&v)[i];
          }
        }
        {  // stage W (wih rows, ldw=7137 odd -> scalar loads)
          const float* wr = wih + (size_t)(n0 + sm) * kGIN + k0 + sq * 4;
#pragma unroll
          for (int i = 0; i < 4; ++i) {
            int kl = sq * 4 + i;
            Ws[kl][sm ^ (8 * sq)] = wr[i];
          }
        }
        __syncthreads();
        if (tid < 256) {
#pragma unroll
          for (int k = 0; k < 32; ++k) {
            float4 a = *(const float4*)&As[k][(ty * 4) ^ (4 * (k & 7))];
            float4 w = *(const float4*)&Ws[k][(tx * 4) ^ (8 * ((k >> 2) & 7))];
            acc[0][0] += a.x * w.x; acc[0][1] += a.x * w.y; acc[0][2] += a.x * w.z; acc[0][3] += a.x * w.w;
            acc[1][0] += a.y * w.x; acc[1][1] += a.y * w.y; acc[1][2] += a.y * w.z; acc[1][3] += a.y * w.w;
            acc[2][0] += a.z * w.x; acc[2][1] += a.z * w.y; acc[2][2] += a.z * w.z; acc[2][3] += a.z * w.w;
            acc[3][0] += a.w * w.x; acc[3][1] += a.w * w.y; acc[3][2] += a.w * w.z; acc[3][3] += a.w * w.w;
          }
        }
        __syncthreads();
      }
      if (tid < 256) {
        float* dst = kh ? giB : giA;
        float4 bb = {0.f, 0.f, 0.f, 0.f};
        if (!kh) bb = *(const float4*)(bih + n0 + tx * 4);
#pragma unroll
        for (int i = 0; i < 4; ++i) {
          float4 o;
          o.x = acc[i][0]; o.y = acc[i][1]; o.z = acc[i][2]; o.w = acc[i][3];
          if (!kh) {
            int tm = targets[(size_t)(m0 + ty * 4 + i) * S + s];
            float4 wt = *(const float4*)(WT + (size_t)tm * 768 + n0 + tx * 4);
            o.x += bb.x + wt.x; o.y += bb.y + wt.y;
            o.z += bb.z + wt.z; o.w += bb.w + wt.w;
          }
          *(float4*)(dst + (size_t)(m0 + ty * 4 + i) * 768 + n0 + tx * 4) = o;
        }
      }
    }
    grid.sync();

    // ================= phase D: GRU update ==================
    {
      const int gid = bid * 512 + tid;
      const int r = gid >> 8, h = gid & 255;
      const size_t gb = (size_t)r * 768;
      const size_t pb = (size_t)r * 1024;
      float i_r = giA[gb + h] + giB[gb + h];
      float i_z = giA[gb + 256 + h] + giB[gb + 256 + h];
      float i_n = giA[gb + 512 + h] + giB[gb + 512 + h];
      float h_r = pgA[pb + 256 + h] + pgB[pb + 256 + h];
      float h_z = pgA[pb + 512 + h] + pgB[pb + 512 + h];
      float h_n = pgA[pb + 768 + h] + pgB[pb + 768 + h];
      float hv = hid[(size_t)r * 256 + h];
      float rr = fast_sig(i_r + h_r);
      float z = fast_sig(i_z + h_z);
      float nn = fast_tanh(i_n + rr * h_n);
      float o = (1.f - z) * nn + z * hv;
      hid[(size_t)r * 256 + h] = o;
      hidd[((size_t)r * S + s) * kH + h] = __float2bfloat16(o);
    }
    grid.sync();
  }
}

// ---------------------------------------------------------------------------
// Final GEMM, bf16 MFMA: C[M,N] = A[M,K] * W[N,K]^T + bias[n]
// 128x128 tile, BK=32, 4 waves in 2x2, 16x16x32 mfma, global_load_lds x16.
// ---------------------------------------------------------------------------
__global__ __launch_bounds__(256) void final_gemm(
    const __hip_bfloat16* __restrict__ A, const __hip_bfloat16* __restrict__ W,
    const float* __restrict__ bias, float* __restrict__ C, int M, int N, int K) {
  __shared__ __align__(16) short As[128 * 32];
  __shared__ __align__(16) short Ws[128 * 32];
  const int tid = threadIdx.x;
  const int wave = tid >> 6, lane = tid & 63;
  const int m0 = blockIdx.x * 128, n0 = blockIdx.y * 128;
  floatx4 acc[4][4] = {};
  const int lr = lane & 15;
  const int lkb = (lane >> 4) * 8;
  const int mloc = (wave & 1) * 64;
  const int nloc = (wave >> 1) * 64;
  const int srow = wave * 16 + (lane >> 2);
  const int skq = (lane & 3) * 8;
  for (int kt = 0; kt < K; kt += 32) {
#pragma unroll
    for (int r = 0; r < 2; ++r) {
      int rowA = r * 64 + srow;
      const __hip_bfloat16* ga = A + (size_t)(m0 + rowA) * K + kt + skq;
      gld_lds16(ga, (char*)As + (size_t)(r * 64 + wave * 16) * 64);
      int rowW = n0 + rowA;
      if (rowW > N - 1) rowW = N - 1;
      const __hip_bfloat16* gw = W + (size_t)rowW * K + kt + skq;
      gld_lds16(gw, (char*)Ws + (size_t)(r * 64 + wave * 16) * 64);
    }
    __syncthreads();
    short8 af[4], wf[4];
#pragma unroll
    for (int i = 0; i < 4; ++i)
      af[i] = *(const short8*)(As + (mloc + i * 16 + lr) * 32 + lkb);
#pragma unroll
    for (int j = 0; j < 4; ++j)
      wf[j] = *(const short8*)(Ws + (nloc + j * 16 + lr) * 32 + lkb);
#pragma unroll
    for (int i = 0; i < 4; ++i)
#pragma unroll
      for (int j = 0; j < 4; ++j)
        acc[i][j] = __builtin_amdgcn_mfma_f32_16x16x32_bf16(af[i], wf[j], acc[i][j], 0, 0, 0);
    __syncthreads();
  }
#pragma unroll
  for (int i = 0; i < 4; ++i) {
#pragma unroll
    for (int j = 0; j < 4; ++j) {
      int col = n0 + nloc + j * 16 + lr;
      if (col < N) {
        int rowb = m0 + mloc + i * 16 + ((lane >> 4) << 2);
        float bs = bias[col];
#pragma unroll
        for (int r = 0; r < 4; ++r)
          C[(size_t)(rowb + r) * N + col] = acc[i][j][r] + bs;
      }
    }
  }
}

// ---------------------------------------------------------------------------
extern "C" void kernel_launch(void* const* d_in, const int* in_sizes, int n_in,
                              void* d_out, int out_size, void* d_ws, size_t ws_size,
                              hipStream_t stream) {
  const float* inputs  = (const float*)d_in[0];
  const int*   targets = (const int*)d_in[1];
  const float* i2h_w   = (const float*)d_in[3];
  const float* h2h_w   = (const float*)d_in[4];
  const float* h2h_b   = (const float*)d_in[5];
  const float* score_w = (const float*)d_in[6];
  const float* gru_wih = (const float*)d_in[7];
  const float* gru_whh = (const float*)d_in[8];
  const float* gru_bih = (const float*)d_in[9];
  const float* gru_bhh = (const float*)d_in[10];
  const float* gen_w   = (const float*)d_in[11];
  const float* gen_b   = (const float*)d_in[12];
  float* out = (float*)d_out;
  const int S = out_size / (kB * kV);  // 25

  // workspace carve (~81 MB)
  char* ws = (char*)d_ws;
  size_t off = 0;
  auto alloc = [&](size_t bytes) {
    void* p = ws + off;
    off += (bytes + 255) & ~(size_t)255;
    return p;
  };
  float* proj = (float*)alloc((size_t)kB * kT * kH * 4);    // 41.9 MB
  float* WT   = (float*)alloc((size_t)kV * 768 * 4);        // 20.4 MB
  float* pgA  = (float*)alloc((size_t)kB * 1024 * 4);       // 2 MB
  float* pgB  = (float*)alloc((size_t)kB * 1024 * 4);       // 2 MB
  float* ctxb = (float*)alloc((size_t)kB * kC * 4);         // 1 MB
  float* giA  = (float*)alloc((size_t)kB * 768 * 4);        // 1.5 MB
  float* giB  = (float*)alloc((size_t)kB * 768 * 4);        // 1.5 MB
  float* hid  = (float*)alloc((size_t)kB * kH * 4);         // 0.5 MB
  __hip_bfloat16* hidd = (__hip_bfloat16*)alloc((size_t)kB * S * kH * 2);
  __hip_bfloat16* gw16 = (__hip_bfloat16*)alloc((size_t)kV * kH * 2);

  cvt_bf16<<<dim3((kV * kH + 255) / 256), 256, 0, stream>>>(gen_w, gw16, kV * kH);

  wt_transpose<<<dim3((kV + 31) / 32, 768 / 32), 256, 0, stream>>>(gru_wih, WT);

  // proj = inputs @ i2h_w^T   [B*T, H], K=C
  proj_gemm<<<dim3(kB * kT / 64, kH / 64), 256, 0, stream>>>(inputs, i2h_w, proj);

  // the entire 25-step recurrence: one cooperative kernel, grid syncs between phases
  void* args[] = {(void*)&inputs, (void*)&proj, (void*)&targets,
                  (void*)&h2h_w, (void*)&h2h_b, (void*)&gru_whh, (void*)&gru_bhh,
                  (void*)&gru_wih, (void*)&gru_bih, (void*)&score_w, (void*)&WT,
                  (void*)&pgA, (void*)&pgB, (void*)&ctxb, (void*)&giA, (void*)&giB,
                  (void*)&hid, (void*)&hidd, (void*)&S};
  hipLaunchCooperativeKernel((const void*)fused_coop, dim3(256), dim3(512), args, 0, stream);

  // probs = hidd @ gen_w^T + gen_b   [B*S, V], K=H (bf16 MFMA)
  final_gemm<<<dim3(kB * S / 128, (kV + 127) / 128), 256, 0, stream>>>(
      hidd, gw16, gen_b, out, kB * S, kV, kH);
}

// Round 3
// 2950.629 us; speedup vs baseline: 1.7167x; 1.7167x over previous
//
#include <hip/hip_runtime.h>
#include <hip/hip_bf16.h>
#include <cstdint>

// Problem constants
constexpr int kB = 512;      // batch
constexpr int kT = 80;       // encoder seq len
constexpr int kC = 512;      // in_channels
constexpr int kH = 256;      // hidden
constexpr int kV = 6625;     // classes
constexpr int kGIN = kC + kV; // 7137, gru_wih leading dim

typedef __attribute__((ext_vector_type(8))) short short8;
typedef __attribute__((ext_vector_type(4))) float floatx4;

__device__ __forceinline__ float fast_tanh(float x) {
  float e = __expf(2.f * x);
  return 1.f - 2.f / (e + 1.f);
}
__device__ __forceinline__ float fast_sig(float x) {
  return 1.f / (1.f + __expf(-x));
}

__device__ __forceinline__ void gld_lds16(const void* g, void* l) {
  __builtin_amdgcn_global_load_lds(
      (const __attribute__((address_space(1))) void*)(uintptr_t)g,
      (__attribute__((address_space(3))) void*)(uintptr_t)l, 16, 0, 0);
}

// ---------------------------------------------------------------------------
// fp32 -> bf16 conversion (gen_w)
// ---------------------------------------------------------------------------
__global__ __launch_bounds__(256) void cvt_bf16(const float* __restrict__ x,
                                                __hip_bfloat16* __restrict__ y,
                                                int n) {
  int i = blockIdx.x * 256 + threadIdx.x;
  if (i < n) y[i] = __float2bfloat16(x[i]);
}

// ---------------------------------------------------------------------------
// One-time transpose with bias fold: WT[v][n] = wih[n][kC+v] + bih[n]
// Makes the per-step one-hot gather (+bias) a contiguous 3KB row read.
// ---------------------------------------------------------------------------
__global__ __launch_bounds__(256) void wt_transpose(const float* __restrict__ wih,
                                                    const float* __restrict__ bih,
                                                    float* __restrict__ WT) {
  __shared__ float tile[32][33];
  const int vb = blockIdx.x * 32, nb = blockIdx.y * 32;
  const int tx = threadIdx.x & 31, ty0 = threadIdx.x >> 5;  // 32 x 8
#pragma unroll
  for (int i = 0; i < 4; ++i) {
    int n = nb + ty0 + i * 8;
    int v = vb + tx;
    tile[ty0 + i * 8][tx] = (v < kV) ? wih[(size_t)n * kGIN + kC + v] : 0.f;
  }
  __syncthreads();
  const float bb = bih[nb + tx];
#pragma unroll
  for (int i = 0; i < 4; ++i) {
    int v = vb + ty0 + i * 8;
    if (v < kV) WT[(size_t)v * 768 + nb + tx] = tile[tx][ty0 + i * 8] + bb;
  }
}

// ---------------------------------------------------------------------------
// One-time repack: wihC[n][c] = wih[n][c] for n<768, c<512.
// Original rows are 7137-float strided (4B-aligned only) -> repack so the
// per-step matvec can use aligned float4 loads.
// ---------------------------------------------------------------------------
__global__ __launch_bounds__(256) void wihc_repack(const float* __restrict__ wih,
                                                   float* __restrict__ wihC) {
  const int n = blockIdx.x;
  const int t = threadIdx.x;
  wihC[(size_t)n * kC + t] = wih[(size_t)n * kGIN + t];
  wihC[(size_t)n * kC + 256 + t] = wih[(size_t)n * kGIN + 256 + t];
}

// ---------------------------------------------------------------------------
// fp32 tiled GEMM: C[M,N] = A[M,K] * W[N,K]^T  (proj = inputs @ i2h_w^T)
// 64x64 tile, BK=16, 256 threads, 4x4 microtile. M=40960, N=256, K=512.
// ---------------------------------------------------------------------------
__global__ __launch_bounds__(256) void proj_gemm(
    const float* __restrict__ A, const float* __restrict__ W,
    float* __restrict__ C) {
  constexpr int lda = kC, ldw = kC, ldc = kH, K = kC;
  __shared__ __align__(16) float As[16][72];
  __shared__ __align__(16) float Ws[16][72];
  const int tid = threadIdx.x;
  const int m0 = blockIdx.x * 64;
  const int n0 = blockIdx.y * 64;
  const int lrow = tid >> 2, lkq = tid & 3;
  const int ty = tid >> 4, tx = tid & 15;
  float acc[4][4] = {};
  for (int k0 = 0; k0 < K; k0 += 16) {
    const float* ap = A + (size_t)(m0 + lrow) * lda + k0 + lkq * 4;
    float4 av = *(const float4*)ap;
    const float* wp = W + (size_t)(n0 + lrow) * ldw + k0 + lkq * 4;
    float4 wv = *(const float4*)wp;
    As[lkq * 4 + 0][lrow] = av.x;
    As[lkq * 4 + 1][lrow] = av.y;
    As[lkq * 4 + 2][lrow] = av.z;
    As[lkq * 4 + 3][lrow] = av.w;
    Ws[lkq * 4 + 0][lrow] = wv.x;
    Ws[lkq * 4 + 1][lrow] = wv.y;
    Ws[lkq * 4 + 2][lrow] = wv.z;
    Ws[lkq * 4 + 3][lrow] = wv.w;
    __syncthreads();
#pragma unroll
    for (int k = 0; k < 16; ++k) {
      float4 a = *(const float4*)&As[k][ty * 4];
      float4 w = *(const float4*)&Ws[k][tx * 4];
      acc[0][0] += a.x * w.x; acc[0][1] += a.x * w.y; acc[0][2] += a.x * w.z; acc[0][3] += a.x * w.w;
      acc[1][0] += a.y * w.x; acc[1][1] += a.y * w.y; acc[1][2] += a.y * w.z; acc[1][3] += a.y * w.w;
      acc[2][0] += a.z * w.x; acc[2][1] += a.z * w.y; acc[2][2] += a.z * w.z; acc[2][3] += a.z * w.w;
      acc[3][0] += a.w * w.x; acc[3][1] += a.w * w.y; acc[3][2] += a.w * w.z; acc[3][3] += a.w * w.w;
    }
    __syncthreads();
  }
#pragma unroll
  for (int i = 0; i < 4; ++i)
#pragma unroll
    for (int j = 0; j < 4; ++j)
      C[(size_t)(m0 + ty * 4 + i) * ldc + n0 + tx * 4 + j] = acc[i][j];
}

// ---------------------------------------------------------------------------
// Persistent fused recurrence: 256 blocks x 1024 threads (16 waves/CU = 47%
// occupancy), each block owns batch rows {2b, 2b+1} for ALL 25 steps.
// Row-wise independence -> no inter-block communication; hidden lives in LDS.
// v2 changes vs the 512-thread version: 2x waves (latency hiding), aligned
// float4 weight loads (wihC), contiguous one-hot gather (WT, bias folded),
// per-block rotation of the weight-row iteration order.
// ---------------------------------------------------------------------------
__global__ __launch_bounds__(1024) void fused_steps(
    const float* __restrict__ inputs,    // [B,T,C]
    const float* __restrict__ proj,      // [B*T,H]
    const int*   __restrict__ targets,   // [B,S] (int32: JAX x64 disabled)
    const float* __restrict__ h2h_w, const float* __restrict__ h2h_b,
    const float* __restrict__ whh,  const float* __restrict__ bhh,
    const float* __restrict__ wihC, const float* __restrict__ WT,
    const float* __restrict__ score_w,
    __hip_bfloat16* __restrict__ hidd,   // [B*S,H]
    int S) {
  __shared__ __align__(16) float hid_s[2][kH];      // 2 KB
  __shared__ __align__(16) float phgh_s[2][1024];   // 8 KB  [ph | gh]
  __shared__ __align__(16) float ctx_s[2][kC];      // 4 KB
  __shared__ __align__(16) float gi_s[2][768];      // 6 KB
  __shared__ __align__(16) float sw_s[kH];          // 1 KB
  __shared__ float e_s[2][kT];                      // 640 B
  const int tid = threadIdx.x;
  const int bid = blockIdx.x;
  const int r0 = bid * 2;
  const int wave = tid >> 6, lane = tid & 63;
  const int g = tid >> 3, q = tid & 7;   // 128 groups of 8 threads

  if (tid < kH) { sw_s[tid] = score_w[tid]; hid_s[0][tid] = 0.f; }
  else if (tid < 2 * kH) { hid_s[1][tid - kH] = 0.f; }
  __syncthreads();

  const int rot3 = bid % 6;  // phase-3 rotation (6 iterations)

  for (int s = 0; s < S; ++s) {
    // ---- phase 1: phgh[r][0:256]=ph=h@h2h^T+b, [256:1024]=gh=h@whh^T+bhh
    // 128 groups x 8 rows each; rotated start so blocks spread over the
    // weight matrix instead of hammering the same lines in lock-step.
#pragma unroll 2
    for (int i = 0; i < 8; ++i) {
      const int n = g + (((i + bid) & 7) << 7);
      const float* wr = (n < kH) ? (h2h_w + (size_t)n * kH)
                                 : (whh + (size_t)(n - kH) * kH);
      float a0 = 0.f, a1 = 0.f, b0 = 0.f, b1 = 0.f;
#pragma unroll
      for (int p = 0; p < 8; p += 2) {
        const int c0 = p * 32 + q * 4;
        const int c1 = c0 + 32;
        float4 wA = *(const float4*)(wr + c0);
        float4 wB = *(const float4*)(wr + c1);
        float4 hA0 = *(const float4*)(&hid_s[0][c0]);
        float4 hB0 = *(const float4*)(&hid_s[0][c1]);
        float4 hA1 = *(const float4*)(&hid_s[1][c0]);
        float4 hB1 = *(const float4*)(&hid_s[1][c1]);
        a0 += wA.x * hA0.x + wA.y * hA0.y + wA.z * hA0.z + wA.w * hA0.w;
        b0 += wB.x * hB0.x + wB.y * hB0.y + wB.z * hB0.z + wB.w * hB0.w;
        a1 += wA.x * hA1.x + wA.y * hA1.y + wA.z * hA1.z + wA.w * hA1.w;
        b1 += wB.x * hB1.x + wB.y * hB1.y + wB.z * hB1.z + wB.w * hB1.w;
      }
      a0 += b0; a1 += b1;
      a0 += __shfl_xor(a0, 1); a0 += __shfl_xor(a0, 2); a0 += __shfl_xor(a0, 4);
      a1 += __shfl_xor(a1, 1); a1 += __shfl_xor(a1, 2); a1 += __shfl_xor(a1, 4);
      if (q == 0) {
        const float bb = (n < kH) ? h2h_b[n] : bhh[n - kH];
        phgh_s[0][n] = a0 + bb;
        phgh_s[1][n] = a1 + bb;
      }
    }
    __syncthreads();

    // ---- phase 2a: e[r][t] = sum_h tanh(proj[r,t,h]+ph[r,h])*sw[h]
    // 160 (r,t) tasks over 16 waves; one wave-pass of 256 elems per task.
    for (int tau = wave; tau < 2 * kT; tau += 16) {
      const int r = tau & 1, t = tau >> 1;
      const float* pp = proj + ((size_t)(r0 + r) * kT + t) * kH + lane * 4;
      float4 pr = *(const float4*)pp;
      float4 ph4 = *(const float4*)(&phgh_s[r][lane * 4]);
      float4 s4 = *(const float4*)(&sw_s[lane * 4]);
      float part = fast_tanh(pr.x + ph4.x) * s4.x +
                   fast_tanh(pr.y + ph4.y) * s4.y +
                   fast_tanh(pr.z + ph4.z) * s4.z +
                   fast_tanh(pr.w + ph4.w) * s4.w;
#pragma unroll
      for (int off = 32; off > 0; off >>= 1) part += __shfl_xor(part, off);
      if (lane == 0) e_s[r][t] = part;
    }
    __syncthreads();

    // ---- phase 2b: softmax over T=80 (wave r handles row r)
    if (wave < 2) {
      const int r = wave;
      float v0 = e_s[r][lane];
      float v1 = (lane < kT - 64) ? e_s[r][64 + lane] : -1e30f;
      float mx = fmaxf(v0, v1);
#pragma unroll
      for (int off = 32; off > 0; off >>= 1) mx = fmaxf(mx, __shfl_xor(mx, off));
      float x0 = __expf(v0 - mx);
      float x1 = (lane < kT - 64) ? __expf(v1 - mx) : 0.f;
      float sm = x0 + x1;
#pragma unroll
      for (int off = 32; off > 0; off >>= 1) sm += __shfl_xor(sm, off);
      float inv = 1.f / sm;
      e_s[r][lane] = x0 * inv;
      if (lane < kT - 64) e_s[r][64 + lane] = x1 * inv;
    }
    __syncthreads();

    // ---- phase 2c: context[r][c] = sum_t alpha[r][t]*inputs[r,t,c]
    // 1024 threads = 2 rows x 512 cols, one element each.
    {
      const int r = tid >> 9, c = tid & 511;
      const float* ib = inputs + ((size_t)(r0 + r) * kT) * kC + c;
      float acc = 0.f;
#pragma unroll 4
      for (int t = 0; t < kT; ++t) acc += e_s[r][t] * ib[(size_t)t * kC];
      ctx_s[r][c] = acc;
    }
    __syncthreads();

    // ---- phase 3: gi[r][n] = ctx[r] @ wihC[n,:]  (bias+onehot folded in WT)
    // 128 groups x 6 rows each, aligned float4 weight loads, rotated start.
    for (int i = 0; i < 6; ++i) {
      int io = i + rot3; if (io >= 6) io -= 6;
      const int n = g + (io << 7);
      const float* wr = wihC + (size_t)n * kC;
      float a0 = 0.f, a1 = 0.f, b0 = 0.f, b1 = 0.f;
#pragma unroll
      for (int p = 0; p < 16; p += 2) {
        const int c0 = p * 32 + q * 4;
        const int c1 = c0 + 32;
        float4 wA = *(const float4*)(wr + c0);
        float4 wB = *(const float4*)(wr + c1);
        float4 xA0 = *(const float4*)(&ctx_s[0][c0]);
        float4 xB0 = *(const float4*)(&ctx_s[0][c1]);
        float4 xA1 = *(const float4*)(&ctx_s[1][c0]);
        float4 xB1 = *(const float4*)(&ctx_s[1][c1]);
        a0 += wA.x * xA0.x + wA.y * xA0.y + wA.z * xA0.z + wA.w * xA0.w;
        b0 += wB.x * xB0.x + wB.y * xB0.y + wB.z * xB0.z + wB.w * xB0.w;
        a1 += wA.x * xA1.x + wA.y * xA1.y + wA.z * xA1.z + wA.w * xA1.w;
        b1 += wB.x * xB1.x + wB.y * xB1.y + wB.z * xB1.z + wB.w * xB1.w;
      }
      a0 += b0; a1 += b1;
      a0 += __shfl_xor(a0, 1); a0 += __shfl_xor(a0, 2); a0 += __shfl_xor(a0, 4);
      a1 += __shfl_xor(a1, 1); a1 += __shfl_xor(a1, 2); a1 += __shfl_xor(a1, 4);
      if (q == 0) {
        gi_s[0][n] = a0;
        gi_s[1][n] = a1;
      }
    }
    __syncthreads();

    // ---- phase 4: GRU update (512 threads = 2 rows x 256 h)
    // i_X = gi_s + WT[tgt] (WT row already includes bih).
    if (tid < 512) {
      const int r = tid >> 8, h = tid & 255;
      const int tg = targets[(size_t)(r0 + r) * S + s];
      const float* wtr = WT + (size_t)tg * 768;
      float i_r = gi_s[r][h] + wtr[h];
      float i_z = gi_s[r][kH + h] + wtr[kH + h];
      float i_n = gi_s[r][2 * kH + h] + wtr[2 * kH + h];
      float h_r = phgh_s[r][kH + h];
      float h_z = phgh_s[r][2 * kH + h];
      float h_n = phgh_s[r][3 * kH + h];
      float hv = hid_s[r][h];
      float rr = fast_sig(i_r + h_r);
      float z = fast_sig(i_z + h_z);
      float nn = fast_tanh(i_n + rr * h_n);
      float o = (1.f - z) * nn + z * hv;
      hid_s[r][h] = o;
      hidd[((size_t)(r0 + r) * S + s) * kH + h] = __float2bfloat16(o);
    }
    __syncthreads();
  }
}

// ---------------------------------------------------------------------------
// Final GEMM, bf16 MFMA: C[M,N] = A[M,K] * W[N,K]^T + bias[n]
// 128x128 tile, BK=32, 4 waves in 2x2, 16x16x32 mfma, global_load_lds x16.
// M=12800 (divides 128), N=6625 (guarded), K=256.
// ---------------------------------------------------------------------------
__global__ __launch_bounds__(256) void final_gemm(
    const __hip_bfloat16* __restrict__ A, const __hip_bfloat16* __restrict__ W,
    const float* __restrict__ bias, float* __restrict__ C, int M, int N, int K) {
  __shared__ __align__(16) short As[128 * 32];
  __shared__ __align__(16) short Ws[128 * 32];
  const int tid = threadIdx.x;
  const int wave = tid >> 6, lane = tid & 63;
  const int m0 = blockIdx.x * 128, n0 = blockIdx.y * 128;
  floatx4 acc[4][4] = {};
  const int lr = lane & 15;
  const int lkb = (lane >> 4) * 8;
  const int mloc = (wave & 1) * 64;
  const int nloc = (wave >> 1) * 64;
  const int srow = wave * 16 + (lane >> 2);
  const int skq = (lane & 3) * 8;
  for (int kt = 0; kt < K; kt += 32) {
#pragma unroll
    for (int r = 0; r < 2; ++r) {
      int rowA = r * 64 + srow;
      const __hip_bfloat16* ga = A + (size_t)(m0 + rowA) * K + kt + skq;
      gld_lds16(ga, (char*)As + (size_t)(r * 64 + wave * 16) * 64);
      int rowW = n0 + rowA;
      if (rowW > N - 1) rowW = N - 1;
      const __hip_bfloat16* gw = W + (size_t)rowW * K + kt + skq;
      gld_lds16(gw, (char*)Ws + (size_t)(r * 64 + wave * 16) * 64);
    }
    __syncthreads();
    short8 af[4], wf[4];
#pragma unroll
    for (int i = 0; i < 4; ++i)
      af[i] = *(const short8*)(As + (mloc + i * 16 + lr) * 32 + lkb);
#pragma unroll
    for (int j = 0; j < 4; ++j)
      wf[j] = *(const short8*)(Ws + (nloc + j * 16 + lr) * 32 + lkb);
#pragma unroll
    for (int i = 0; i < 4; ++i)
#pragma unroll
      for (int j = 0; j < 4; ++j)
        acc[i][j] = __builtin_amdgcn_mfma_f32_16x16x32_bf16(af[i], wf[j], acc[i][j], 0, 0, 0);
    __syncthreads();
  }
#pragma unroll
  for (int i = 0; i < 4; ++i) {
#pragma unroll
    for (int j = 0; j < 4; ++j) {
      int col = n0 + nloc + j * 16 + lr;
      if (col < N) {
        int rowb = m0 + mloc + i * 16 + ((lane >> 4) << 2);
        float bs = bias[col];
#pragma unroll
        for (int r = 0; r < 4; ++r)
          C[(size_t)(rowb + r) * N + col] = acc[i][j][r] + bs;
      }
    }
  }
}

// ---------------------------------------------------------------------------
extern "C" void kernel_launch(void* const* d_in, const int* in_sizes, int n_in,
                              void* d_out, int out_size, void* d_ws, size_t ws_size,
                              hipStream_t stream) {
  const float* inputs  = (const float*)d_in[0];
  const int*   targets = (const int*)d_in[1];
  // d_in[2] = batch_max_length (device scalar); S derived from out_size instead
  const float* i2h_w   = (const float*)d_in[3];
  const float* h2h_w   = (const float*)d_in[4];
  const float* h2h_b   = (const float*)d_in[5];
  const float* score_w = (const float*)d_in[6];
  const float* gru_wih = (const float*)d_in[7];
  const float* gru_whh = (const float*)d_in[8];
  const float* gru_bih = (const float*)d_in[9];
  const float* gru_bhh = (const float*)d_in[10];
  const float* gen_w   = (const float*)d_in[11];
  const float* gen_b   = (const float*)d_in[12];
  float* out = (float*)d_out;
  const int S = out_size / (kB * kV);  // 25

  // workspace carve (~66 MB)
  char* ws = (char*)d_ws;
  size_t off = 0;
  auto alloc = [&](size_t bytes) {
    void* p = ws + off;
    off += (bytes + 255) & ~(size_t)255;
    return p;
  };
  float* proj = (float*)alloc((size_t)kB * kT * kH * 4);    // 41.9 MB
  float* WT   = (float*)alloc((size_t)kV * 768 * 4);        // 20.4 MB
  float* wihC = (float*)alloc((size_t)768 * kC * 4);        // 1.5 MB
  __hip_bfloat16* hidd = (__hip_bfloat16*)alloc((size_t)kB * S * kH * 2);
  __hip_bfloat16* gw16 = (__hip_bfloat16*)alloc((size_t)kV * kH * 2);

  cvt_bf16<<<dim3((kV * kH + 255) / 256), 256, 0, stream>>>(gen_w, gw16, kV * kH);

  wt_transpose<<<dim3((kV + 31) / 32, 768 / 32), 256, 0, stream>>>(gru_wih, gru_bih, WT);
  wihc_repack<<<dim3(768), 256, 0, stream>>>(gru_wih, wihC);

  // proj = inputs @ i2h_w^T   [B*T, H], K=C
  proj_gemm<<<dim3(kB * kT / 64, kH / 64), 256, 0, stream>>>(inputs, i2h_w, proj);

  // the entire 25-step recurrence: one persistent kernel, no grid syncs
  fused_steps<<<dim3(kB / 2), 1024, 0, stream>>>(
      inputs, proj, targets, h2h_w, h2h_b, gru_whh, gru_bhh,
      wihC, WT, score_w, hidd, S);

  // probs = hidd @ gen_w^T + gen_b   [B*S, V], K=H (bf16 MFMA)
  final_gemm<<<dim3(kB * S / 128, (kV + 127) / 128), 256, 0, stream>>>(
      hidd, gw16, gen_b, out, kB * S, kV, kH);
}

// Round 4
// 2528.502 us; speedup vs baseline: 2.0033x; 1.1669x over previous
//
#include <hip/hip_runtime.h>
#include <hip/hip_bf16.h>
#include <cstdint>

// Problem constants
constexpr int kB = 512;      // batch
constexpr int kT = 80;       // encoder seq len
constexpr int kC = 512;      // in_channels
constexpr int kH = 256;      // hidden
constexpr int kV = 6625;     // classes
constexpr int kGIN = kC + kV; // 7137, gru_wih leading dim

typedef __attribute__((ext_vector_type(8))) short short8;
typedef __attribute__((ext_vector_type(4))) float floatx4;

__device__ __forceinline__ float fast_tanh(float x) {
  float e = __expf(2.f * x);
  return 1.f - 2.f / (e + 1.f);
}
__device__ __forceinline__ float fast_sig(float x) {
  return 1.f / (1.f + __expf(-x));
}

__device__ __forceinline__ void gld_lds16(const void* g, void* l) {
  __builtin_amdgcn_global_load_lds(
      (const __attribute__((address_space(1))) void*)(uintptr_t)g,
      (__attribute__((address_space(3))) void*)(uintptr_t)l, 16, 0, 0);
}

// ---------------------------------------------------------------------------
// fp32 -> bf16 conversion (gen_w)
// ---------------------------------------------------------------------------
__global__ __launch_bounds__(256) void cvt_bf16(const float* __restrict__ x,
                                                __hip_bfloat16* __restrict__ y,
                                                int n) {
  int i = blockIdx.x * 256 + threadIdx.x;
  if (i < n) y[i] = __float2bfloat16(x[i]);
}

// ---------------------------------------------------------------------------
// One-time transpose with bias fold: WT[v][n] = wih[n][kC+v] + bih[n]
// Makes the per-step one-hot gather (+bias) a contiguous 3KB row read.
// ---------------------------------------------------------------------------
__global__ __launch_bounds__(256) void wt_transpose(const float* __restrict__ wih,
                                                    const float* __restrict__ bih,
                                                    float* __restrict__ WT) {
  __shared__ float tile[32][33];
  const int vb = blockIdx.x * 32, nb = blockIdx.y * 32;
  const int tx = threadIdx.x & 31, ty0 = threadIdx.x >> 5;  // 32 x 8
#pragma unroll
  for (int i = 0; i < 4; ++i) {
    int n = nb + ty0 + i * 8;
    int v = vb + tx;
    tile[ty0 + i * 8][tx] = (v < kV) ? wih[(size_t)n * kGIN + kC + v] : 0.f;
  }
  __syncthreads();
  const float bb = bih[nb + tx];
#pragma unroll
  for (int i = 0; i < 4; ++i) {
    int v = vb + ty0 + i * 8;
    if (v < kV) WT[(size_t)v * 768 + nb + tx] = tile[tx][ty0 + i * 8] + bb;
  }
}

// ---------------------------------------------------------------------------
// One-time repack: wihC[n][c] = wih[n][c] for n<768, c<512 (aligned float4).
// ---------------------------------------------------------------------------
__global__ __launch_bounds__(256) void wihc_repack(const float* __restrict__ wih,
                                                   float* __restrict__ wihC) {
  const int n = blockIdx.x;
  const int t = threadIdx.x;
  wihC[(size_t)n * kC + t] = wih[(size_t)n * kGIN + t];
  wihC[(size_t)n * kC + 256 + t] = wih[(size_t)n * kGIN + 256 + t];
}

// ---------------------------------------------------------------------------
// fp32 tiled GEMM: C[M,N] = A[M,K] * W[N,K]^T  (proj = inputs @ i2h_w^T)
// 64x64 tile, BK=16, 256 threads, 4x4 microtile. M=40960, N=256, K=512.
// ---------------------------------------------------------------------------
__global__ __launch_bounds__(256) void proj_gemm(
    const float* __restrict__ A, const float* __restrict__ W,
    float* __restrict__ C) {
  constexpr int lda = kC, ldw = kC, ldc = kH, K = kC;
  __shared__ __align__(16) float As[16][72];
  __shared__ __align__(16) float Ws[16][72];
  const int tid = threadIdx.x;
  const int m0 = blockIdx.x * 64;
  const int n0 = blockIdx.y * 64;
  const int lrow = tid >> 2, lkq = tid & 3;
  const int ty = tid >> 4, tx = tid & 15;
  float acc[4][4] = {};
  for (int k0 = 0; k0 < K; k0 += 16) {
    const float* ap = A + (size_t)(m0 + lrow) * lda + k0 + lkq * 4;
    float4 av = *(const float4*)ap;
    const float* wp = W + (size_t)(n0 + lrow) * ldw + k0 + lkq * 4;
    float4 wv = *(const float4*)wp;
    As[lkq * 4 + 0][lrow] = av.x;
    As[lkq * 4 + 1][lrow] = av.y;
    As[lkq * 4 + 2][lrow] = av.z;
    As[lkq * 4 + 3][lrow] = av.w;
    Ws[lkq * 4 + 0][lrow] = wv.x;
    Ws[lkq * 4 + 1][lrow] = wv.y;
    Ws[lkq * 4 + 2][lrow] = wv.z;
    Ws[lkq * 4 + 3][lrow] = wv.w;
    __syncthreads();
#pragma unroll
    for (int k = 0; k < 16; ++k) {
      float4 a = *(const float4*)&As[k][ty * 4];
      float4 w = *(const float4*)&Ws[k][tx * 4];
      acc[0][0] += a.x * w.x; acc[0][1] += a.x * w.y; acc[0][2] += a.x * w.z; acc[0][3] += a.x * w.w;
      acc[1][0] += a.y * w.x; acc[1][1] += a.y * w.y; acc[1][2] += a.y * w.z; acc[1][3] += a.y * w.w;
      acc[2][0] += a.z * w.x; acc[2][1] += a.z * w.y; acc[2][2] += a.z * w.z; acc[2][3] += a.z * w.w;
      acc[3][0] += a.w * w.x; acc[3][1] += a.w * w.y; acc[3][2] += a.w * w.z; acc[3][3] += a.w * w.w;
    }
    __syncthreads();
  }
#pragma unroll
  for (int i = 0; i < 4; ++i)
#pragma unroll
    for (int j = 0; j < 4; ++j)
      C[(size_t)(m0 + ty * 4 + i) * ldc + n0 + tx * 4 + j] = acc[i][j];
}

// ---------------------------------------------------------------------------
// Persistent fused recurrence: 256 blocks x 1024 threads, block owns batch
// rows {2b, 2b+1} for all 25 steps; hidden lives in LDS.
// v3: the block's proj slice (164 KB = 40 floats/thread) is preloaded into
// REGISTERS once and reused for all 25 steps -- removes 42 MB/step of
// global traffic and shrinks the streamed footprint so inputs stay
// L3-resident across steps.
// ---------------------------------------------------------------------------
__global__ __launch_bounds__(1024) void fused_steps(
    const float* __restrict__ inputs,    // [B,T,C]
    const float* __restrict__ proj,      // [B*T,H]
    const int*   __restrict__ targets,   // [B,S] (int32: JAX x64 disabled)
    const float* __restrict__ h2h_w, const float* __restrict__ h2h_b,
    const float* __restrict__ whh,  const float* __restrict__ bhh,
    const float* __restrict__ wihC, const float* __restrict__ WT,
    const float* __restrict__ score_w,
    __hip_bfloat16* __restrict__ hidd,   // [B*S,H]
    int S) {
  __shared__ __align__(16) float hid_s[2][kH];      // 2 KB
  __shared__ __align__(16) float phgh_s[2][1024];   // 8 KB  [ph | gh]
  __shared__ __align__(16) float ctx_s[2][kC];      // 4 KB
  __shared__ __align__(16) float gi_s[2][768];      // 6 KB
  __shared__ float e_s[2][kT];                      // 640 B
  const int tid = threadIdx.x;
  const int bid = blockIdx.x;
  const int r0 = bid * 2;
  const int wave = tid >> 6, lane = tid & 63;
  const int g = tid >> 3, q = tid & 7;   // 128 groups of 8 threads

  if (tid < kH) hid_s[0][tid] = 0.f;
  else if (tid < 2 * kH) hid_s[1][tid - kH] = 0.f;

  // score_w slice for this lane (fixed per thread) -> 4 regs
  const float4 s4 = *(const float4*)(score_w + lane * 4);

  // ---- preload the block's proj slice into registers (40 VGPRs/thread).
  // Task mapping matches phase 2a exactly: task tau = wave + 16*k,
  // r = tau&1, t = tau>>1, h-slice = lane*4..lane*4+3.
  float4 pr[10];
#pragma unroll
  for (int k = 0; k < 10; ++k) {
    const int tau = wave + 16 * k;
    const int r = tau & 1, t = tau >> 1;
    pr[k] = *(const float4*)(proj + ((size_t)(r0 + r) * kT + t) * kH + lane * 4);
  }
  __syncthreads();

  const int rot3 = bid % 6;  // phase-3 rotation (6 iterations)

  for (int s = 0; s < S; ++s) {
    // ---- phase 1: phgh[r][0:256]=ph=h@h2h^T+b, [256:1024]=gh=h@whh^T+bhh
    // 128 groups x 8 rows each; rotated start so blocks spread over the
    // weight matrix instead of hammering the same lines in lock-step.
#pragma unroll 2
    for (int i = 0; i < 8; ++i) {
      const int n = g + (((i + bid) & 7) << 7);
      const float* wr = (n < kH) ? (h2h_w + (size_t)n * kH)
                                 : (whh + (size_t)(n - kH) * kH);
      float a0 = 0.f, a1 = 0.f, b0 = 0.f, b1 = 0.f;
#pragma unroll
      for (int p = 0; p < 8; p += 2) {
        const int c0 = p * 32 + q * 4;
        const int c1 = c0 + 32;
        float4 wA = *(const float4*)(wr + c0);
        float4 wB = *(const float4*)(wr + c1);
        float4 hA0 = *(const float4*)(&hid_s[0][c0]);
        float4 hB0 = *(const float4*)(&hid_s[0][c1]);
        float4 hA1 = *(const float4*)(&hid_s[1][c0]);
        float4 hB1 = *(const float4*)(&hid_s[1][c1]);
        a0 += wA.x * hA0.x + wA.y * hA0.y + wA.z * hA0.z + wA.w * hA0.w;
        b0 += wB.x * hB0.x + wB.y * hB0.y + wB.z * hB0.z + wB.w * hB0.w;
        a1 += wA.x * hA1.x + wA.y * hA1.y + wA.z * hA1.z + wA.w * hA1.w;
        b1 += wB.x * hB1.x + wB.y * hB1.y + wB.z * hB1.z + wB.w * hB1.w;
      }
      a0 += b0; a1 += b1;
      a0 += __shfl_xor(a0, 1); a0 += __shfl_xor(a0, 2); a0 += __shfl_xor(a0, 4);
      a1 += __shfl_xor(a1, 1); a1 += __shfl_xor(a1, 2); a1 += __shfl_xor(a1, 4);
      if (q == 0) {
        const float bb = (n < kH) ? h2h_b[n] : bhh[n - kH];
        phgh_s[0][n] = a0 + bb;
        phgh_s[1][n] = a1 + bb;
      }
    }
    __syncthreads();

    // ---- phase 2a: e[r][t] = sum_h tanh(proj[r,t,h]+ph[r,h])*sw[h]
    // proj slice already in registers -> pure VALU + LDS.
#pragma unroll
    for (int k = 0; k < 10; ++k) {
      const int tau = wave + 16 * k;
      const int r = tau & 1, t = tau >> 1;
      float4 ph4 = *(const float4*)(&phgh_s[r][lane * 4]);
      float part = fast_tanh(pr[k].x + ph4.x) * s4.x +
                   fast_tanh(pr[k].y + ph4.y) * s4.y +
                   fast_tanh(pr[k].z + ph4.z) * s4.z +
                   fast_tanh(pr[k].w + ph4.w) * s4.w;
#pragma unroll
      for (int off = 32; off > 0; off >>= 1) part += __shfl_xor(part, off);
      if (lane == 0) e_s[r][t] = part;
    }
    __syncthreads();

    // ---- phase 2b: softmax over T=80 (wave r handles row r)
    if (wave < 2) {
      const int r = wave;
      float v0 = e_s[r][lane];
      float v1 = (lane < kT - 64) ? e_s[r][64 + lane] : -1e30f;
      float mx = fmaxf(v0, v1);
#pragma unroll
      for (int off = 32; off > 0; off >>= 1) mx = fmaxf(mx, __shfl_xor(mx, off));
      float x0 = __expf(v0 - mx);
      float x1 = (lane < kT - 64) ? __expf(v1 - mx) : 0.f;
      float sm = x0 + x1;
#pragma unroll
      for (int off = 32; off > 0; off >>= 1) sm += __shfl_xor(sm, off);
      float inv = 1.f / sm;
      e_s[r][lane] = x0 * inv;
      if (lane < kT - 64) e_s[r][64 + lane] = x1 * inv;
    }
    __syncthreads();

    // ---- phase 2c: context[r][c] = sum_t alpha[r][t]*inputs[r,t,c]
    // 1024 threads = 2 rows x 512 cols, one element each.
    {
      const int r = tid >> 9, c = tid & 511;
      const float* ib = inputs + ((size_t)(r0 + r) * kT) * kC + c;
      float acc = 0.f;
#pragma unroll 4
      for (int t = 0; t < kT; ++t) acc += e_s[r][t] * ib[(size_t)t * kC];
      ctx_s[r][c] = acc;
    }
    __syncthreads();

    // ---- phase 3: gi[r][n] = ctx[r] @ wihC[n,:]  (bias+onehot folded in WT)
    // 128 groups x 6 rows each, aligned float4 weight loads, rotated start.
    for (int i = 0; i < 6; ++i) {
      int io = i + rot3; if (io >= 6) io -= 6;
      const int n = g + (io << 7);
      const float* wr = wihC + (size_t)n * kC;
      float a0 = 0.f, a1 = 0.f, b0 = 0.f, b1 = 0.f;
#pragma unroll
      for (int p = 0; p < 16; p += 2) {
        const int c0 = p * 32 + q * 4;
        const int c1 = c0 + 32;
        float4 wA = *(const float4*)(wr + c0);
        float4 wB = *(const float4*)(wr + c1);
        float4 xA0 = *(const float4*)(&ctx_s[0][c0]);
        float4 xB0 = *(const float4*)(&ctx_s[0][c1]);
        float4 xA1 = *(const float4*)(&ctx_s[1][c0]);
        float4 xB1 = *(const float4*)(&ctx_s[1][c1]);
        a0 += wA.x * xA0.x + wA.y * xA0.y + wA.z * xA0.z + wA.w * xA0.w;
        b0 += wB.x * xB0.x + wB.y * xB0.y + wB.z * xB0.z + wB.w * xB0.w;
        a1 += wA.x * xA1.x + wA.y * xA1.y + wA.z * xA1.z + wA.w * xA1.w;
        b1 += wB.x * xB1.x + wB.y * xB1.y + wB.z * xB1.z + wB.w * xB1.w;
      }
      a0 += b0; a1 += b1;
      a0 += __shfl_xor(a0, 1); a0 += __shfl_xor(a0, 2); a0 += __shfl_xor(a0, 4);
      a1 += __shfl_xor(a1, 1); a1 += __shfl_xor(a1, 2); a1 += __shfl_xor(a1, 4);
      if (q == 0) {
        gi_s[0][n] = a0;
        gi_s[1][n] = a1;
      }
    }
    __syncthreads();

    // ---- phase 4: GRU update (512 threads = 2 rows x 256 h)
    // i_X = gi_s + WT[tgt] (WT row already includes bih).
    if (tid < 512) {
      const int r = tid >> 8, h = tid & 255;
      const int tg = targets[(size_t)(r0 + r) * S + s];
      const float* wtr = WT + (size_t)tg * 768;
      float i_r = gi_s[r][h] + wtr[h];
      float i_z = gi_s[r][kH + h] + wtr[kH + h];
      float i_n = gi_s[r][2 * kH + h] + wtr[2 * kH + h];
      float h_r = phgh_s[r][kH + h];
      float h_z = phgh_s[r][2 * kH + h];
      float h_n = phgh_s[r][3 * kH + h];
      float hv = hid_s[r][h];
      float rr = fast_sig(i_r + h_r);
      float z = fast_sig(i_z + h_z);
      float nn = fast_tanh(i_n + rr * h_n);
      float o = (1.f - z) * nn + z * hv;
      hid_s[r][h] = o;
      hidd[((size_t)(r0 + r) * S + s) * kH + h] = __float2bfloat16(o);
    }
    __syncthreads();
  }
}

// ---------------------------------------------------------------------------
// Final GEMM, bf16 MFMA: C[M,N] = A[M,K] * W[N,K]^T + bias[n]
// 128x128 tile, BK=32, 4 waves in 2x2, 16x16x32 mfma, global_load_lds x16.
// M=12800 (divides 128), N=6625 (guarded), K=256.
// ---------------------------------------------------------------------------
__global__ __launch_bounds__(256) void final_gemm(
    const __hip_bfloat16* __restrict__ A, const __hip_bfloat16* __restrict__ W,
    const float* __restrict__ bias, float* __restrict__ C, int M, int N, int K) {
  __shared__ __align__(16) short As[128 * 32];
  __shared__ __align__(16) short Ws[128 * 32];
  const int tid = threadIdx.x;
  const int wave = tid >> 6, lane = tid & 63;
  const int m0 = blockIdx.x * 128, n0 = blockIdx.y * 128;
  floatx4 acc[4][4] = {};
  const int lr = lane & 15;
  const int lkb = (lane >> 4) * 8;
  const int mloc = (wave & 1) * 64;
  const int nloc = (wave >> 1) * 64;
  const int srow = wave * 16 + (lane >> 2);
  const int skq = (lane & 3) * 8;
  for (int kt = 0; kt < K; kt += 32) {
#pragma unroll
    for (int r = 0; r < 2; ++r) {
      int rowA = r * 64 + srow;
      const __hip_bfloat16* ga = A + (size_t)(m0 + rowA) * K + kt + skq;
      gld_lds16(ga, (char*)As + (size_t)(r * 64 + wave * 16) * 64);
      int rowW = n0 + rowA;
      if (rowW > N - 1) rowW = N - 1;
      const __hip_bfloat16* gw = W + (size_t)rowW * K + kt + skq;
      gld_lds16(gw, (char*)Ws + (size_t)(r * 64 + wave * 16) * 64);
    }
    __syncthreads();
    short8 af[4], wf[4];
#pragma unroll
    for (int i = 0; i < 4; ++i)
      af[i] = *(const short8*)(As + (mloc + i * 16 + lr) * 32 + lkb);
#pragma unroll
    for (int j = 0; j < 4; ++j)
      wf[j] = *(const short8*)(Ws + (nloc + j * 16 + lr) * 32 + lkb);
#pragma unroll
    for (int i = 0; i < 4; ++i)
#pragma unroll
      for (int j = 0; j < 4; ++j)
        acc[i][j] = __builtin_amdgcn_mfma_f32_16x16x32_bf16(af[i], wf[j], acc[i][j], 0, 0, 0);
    __syncthreads();
  }
#pragma unroll
  for (int i = 0; i < 4; ++i) {
#pragma unroll
    for (int j = 0; j < 4; ++j) {
      int col = n0 + nloc + j * 16 + lr;
      if (col < N) {
        int rowb = m0 + mloc + i * 16 + ((lane >> 4) << 2);
        float bs = bias[col];
#pragma unroll
        for (int r = 0; r < 4; ++r)
          C[(size_t)(rowb + r) * N + col] = acc[i][j][r] + bs;
      }
    }
  }
}

// ---------------------------------------------------------------------------
extern "C" void kernel_launch(void* const* d_in, const int* in_sizes, int n_in,
                              void* d_out, int out_size, void* d_ws, size_t ws_size,
                              hipStream_t stream) {
  const float* inputs  = (const float*)d_in[0];
  const int*   targets = (const int*)d_in[1];
  // d_in[2] = batch_max_length (device scalar); S derived from out_size instead
  const float* i2h_w   = (const float*)d_in[3];
  const float* h2h_w   = (const float*)d_in[4];
  const float* h2h_b   = (const float*)d_in[5];
  const float* score_w = (const float*)d_in[6];
  const float* gru_wih = (const float*)d_in[7];
  const float* gru_whh = (const float*)d_in[8];
  const float* gru_bih = (const float*)d_in[9];
  const float* gru_bhh = (const float*)d_in[10];
  const float* gen_w   = (const float*)d_in[11];
  const float* gen_b   = (const float*)d_in[12];
  float* out = (float*)d_out;
  const int S = out_size / (kB * kV);  // 25

  // workspace carve (~66 MB)
  char* ws = (char*)d_ws;
  size_t off = 0;
  auto alloc = [&](size_t bytes) {
    void* p = ws + off;
    off += (bytes + 255) & ~(size_t)255;
    return p;
  };
  float* proj = (float*)alloc((size_t)kB * kT * kH * 4);    // 41.9 MB
  float* WT   = (float*)alloc((size_t)kV * 768 * 4);        // 20.4 MB
  float* wihC = (float*)alloc((size_t)768 * kC * 4);        // 1.5 MB
  __hip_bfloat16* hidd = (__hip_bfloat16*)alloc((size_t)kB * S * kH * 2);
  __hip_bfloat16* gw16 = (__hip_bfloat16*)alloc((size_t)kV * kH * 2);

  cvt_bf16<<<dim3((kV * kH + 255) / 256), 256, 0, stream>>>(gen_w, gw16, kV * kH);

  wt_transpose<<<dim3((kV + 31) / 32, 768 / 32), 256, 0, stream>>>(gru_wih, gru_bih, WT);
  wihc_repack<<<dim3(768), 256, 0, stream>>>(gru_wih, wihC);

  // proj = inputs @ i2h_w^T   [B*T, H], K=C
  proj_gemm<<<dim3(kB * kT / 64, kH / 64), 256, 0, stream>>>(inputs, i2h_w, proj);

  // the entire 25-step recurrence: one persistent kernel, no grid syncs
  fused_steps<<<dim3(kB / 2), 1024, 0, stream>>>(
      inputs, proj, targets, h2h_w, h2h_b, gru_whh, gru_bhh,
      wihC, WT, score_w, hidd, S);

  // probs = hidd @ gen_w^T + gen_b   [B*S, V], K=H (bf16 MFMA)
  final_gemm<<<dim3(kB * S / 128, (kV + 127) / 128), 256, 0, stream>>>(
      hidd, gw16, gen_b, out, kB * S, kV, kH);
}